// Round 1
// baseline (334.100 us; speedup 1.0000x reference)
//
#include <hip/hip_runtime.h>
#include <hip/hip_bf16.h>
#include <stdint.h>

// Problem constants: B=4, S=2048, D=1024, H=16, HD=64
#define B_  4
#define S_  2048
#define D_  1024
#define H_  16
#define HD_ 64

typedef __attribute__((ext_vector_type(8))) short          s16x8;   // MFMA A/B frag (8 bf16)
typedef __attribute__((ext_vector_type(4))) float          f32x4;   // MFMA C/D frag
typedef __attribute__((ext_vector_type(8))) unsigned short u16x8;   // 16B bf16 chunk

__device__ __forceinline__ unsigned short f2bf(float f) {
  union { float f; unsigned int u; } v; v.f = f;
  unsigned int u = v.u;
  u += 0x7fffu + ((u >> 16) & 1u);       // RNE
  return (unsigned short)(u >> 16);
}

// ---------------------------------------------------------------- converts
__global__ void k_cvt(const float* __restrict__ src, unsigned short* __restrict__ dst, int n4) {
  int i = blockIdx.x * blockDim.x + threadIdx.x;
  int stride = gridDim.x * blockDim.x;
  for (int j = i; j < n4; j += stride) {
    float4 v = reinterpret_cast<const float4*>(src)[j];
    ushort4 o;
    o.x = f2bf(v.x); o.y = f2bf(v.y); o.z = f2bf(v.z); o.w = f2bf(v.w);
    reinterpret_cast<ushort4*>(dst)[j] = o;
  }
}

// fp32 [R][C] -> bf16 [C][R]   (weights -> B^T layout for gemm-BT)
__global__ void k_tpose_cvt(const float* __restrict__ src, unsigned short* __restrict__ dst,
                            int R, int C) {
  __shared__ unsigned short tile[64][72];          // 144B stride -> 2-way banks (free)
  int c0 = blockIdx.x * 64, r0 = blockIdx.y * 64;
  int tx = threadIdx.x & 63, ty = threadIdx.x >> 6;
#pragma unroll
  for (int i = 0; i < 16; ++i) {
    int r = ty * 16 + i;
    tile[r][tx] = f2bf(src[(size_t)(r0 + r) * C + c0 + tx]);
  }
  __syncthreads();
#pragma unroll
  for (int i = 0; i < 16; ++i) {
    int c = ty * 16 + i;
    dst[(size_t)(c0 + c) * R + r0 + tx] = tile[tx][c];
  }
}

// bf16 V [BH][S][HD] -> Vt [BH][HD][S]
__global__ void k_tpose_v(const unsigned short* __restrict__ src, unsigned short* __restrict__ dst) {
  __shared__ unsigned short tile[64][72];
  int s0 = blockIdx.x * 64, bh = blockIdx.y;
  int tx = threadIdx.x & 63, ty = threadIdx.x >> 6;
  const unsigned short* sb = src + (size_t)bh * S_ * HD_;
  unsigned short*       db = dst + (size_t)bh * S_ * HD_;
#pragma unroll
  for (int i = 0; i < 16; ++i) {
    int r = ty * 16 + i;
    tile[r][tx] = sb[(size_t)(s0 + r) * HD_ + tx];
  }
  __syncthreads();
#pragma unroll
  for (int i = 0; i < 16; ++i) {
    int hd = ty * 16 + i;
    db[(size_t)hd * S_ + s0 + tx] = tile[tx][hd];
  }
}

// ---------------------------------------------------------------- GEMM core
// C[128x128] = A[M,K] @ Bt[N,K]^T ; bf16 in, f32 acc. 256 thr = 4 waves (2x2),
// wave tile 64x64 = 4x4 frags of mfma_f32_16x16x32_bf16. Reg-staged LDS with
// XOR chunk swizzle: chunk' = chunk ^ ((row>>1)&3)  -> conflict-free b128 r/w.
__device__ __forceinline__ void gemm_core(const unsigned short* __restrict__ A,
                                          const unsigned short* __restrict__ Bt,
                                          int K, int m0, int n0,
                                          unsigned short* sm, f32x4 acc[4][4]) {
  const int t = threadIdx.x;
  const int w = t >> 6, l = t & 63;
  const int wm = w >> 1, wn = w & 1;
  const int lo = l & 15, hi = l >> 4;

  // staging assignment: 512 chunks of 16B per matrix tile (128 rows x 4)
  const int ci0 = t, ci1 = t + 256;
  const int r0c = ci0 >> 2, o0c = ci0 & 3;
  const int r1c = ci1 >> 2, o1c = ci1 & 3;
  const int swz0 = r0c * 32 + ((o0c ^ ((r0c >> 1) & 3)) << 3);
  const int swz1 = r1c * 32 + ((o1c ^ ((r1c >> 1) & 3)) << 3);
  const unsigned short* gA0 = A  + (size_t)(m0 + r0c) * K + o0c * 8;
  const unsigned short* gA1 = A  + (size_t)(m0 + r1c) * K + o1c * 8;
  const unsigned short* gB0 = Bt + (size_t)(n0 + r0c) * K + o0c * 8;
  const unsigned short* gB1 = Bt + (size_t)(n0 + r1c) * K + o1c * 8;

#pragma unroll
  for (int m = 0; m < 4; ++m)
#pragma unroll
    for (int n = 0; n < 4; ++n)
      acc[m][n] = (f32x4){0.f, 0.f, 0.f, 0.f};

  const int NT = K >> 5;  // BK = 32
  u16x8 ra0 = *(const u16x8*)gA0, ra1 = *(const u16x8*)gA1;
  u16x8 rb0 = *(const u16x8*)gB0, rb1 = *(const u16x8*)gB1;

  for (int kt = 0; kt < NT; ++kt) {
    unsigned short* buf = sm + (kt & 1) * 8192;   // A: [0,4096) B: [4096,8192)
    if (kt) __syncthreads();                      // prev readers of this buf done
    *(u16x8*)(buf + swz0)        = ra0;
    *(u16x8*)(buf + swz1)        = ra1;
    *(u16x8*)(buf + 4096 + swz0) = rb0;
    *(u16x8*)(buf + 4096 + swz1) = rb1;
    if (kt + 1 < NT) {                            // issue next loads early
      int k0 = (kt + 1) << 5;
      ra0 = *(const u16x8*)(gA0 + k0);
      ra1 = *(const u16x8*)(gA1 + k0);
      rb0 = *(const u16x8*)(gB0 + k0);
      rb1 = *(const u16x8*)(gB1 + k0);
    }
    __syncthreads();                              // stage visible
    const unsigned short* Ab = buf;
    const unsigned short* Bb = buf + 4096;
    s16x8 af[4], bfr[4];
#pragma unroll
    for (int m = 0; m < 4; ++m) {
      int row = wm * 64 + m * 16 + lo;
      af[m] = *(const s16x8*)(Ab + row * 32 + ((hi ^ ((row >> 1) & 3)) << 3));
    }
#pragma unroll
    for (int n = 0; n < 4; ++n) {
      int row = wn * 64 + n * 16 + lo;
      bfr[n] = *(const s16x8*)(Bb + row * 32 + ((hi ^ ((row >> 1) & 3)) << 3));
    }
#pragma unroll
    for (int m = 0; m < 4; ++m)
#pragma unroll
      for (int n = 0; n < 4; ++n)
        acc[m][n] = __builtin_amdgcn_mfma_f32_16x16x32_bf16(af[m], bfr[n], acc[m][n], 0, 0, 0);
  }
}

// GEMM1: qkv = x @ W_attn + b ; epilogue scatters into Q/K/V [B,H,S,HD] bf16
__global__ __launch_bounds__(256, 2)
void k_gemm_qkv(const unsigned short* __restrict__ A, const unsigned short* __restrict__ Bt,
                const float* __restrict__ bias,
                unsigned short* __restrict__ Qh, unsigned short* __restrict__ Kh,
                unsigned short* __restrict__ Vh) {
  __shared__ unsigned short sm[2 * 8192];
  const int m0 = blockIdx.y * 128, n0 = blockIdx.x * 128;
  f32x4 acc[4][4];
  gemm_core(A, Bt, 1024, m0, n0, sm, acc);
  const int t = threadIdx.x, w = t >> 6, l = t & 63;
  const int wm = w >> 1, wn = w & 1, lo = l & 15, hi = l >> 4;
#pragma unroll
  for (int m = 0; m < 4; ++m)
#pragma unroll
    for (int n = 0; n < 4; ++n) {
      int col = n0 + wn * 64 + n * 16 + lo;           // 0..3071
      float bv = bias[col];
      int sel = col >> 10, cw = col & 1023, h = cw >> 6, hd = cw & 63;
      unsigned short* dst = (sel == 0) ? Qh : ((sel == 1) ? Kh : Vh);
#pragma unroll
      for (int r = 0; r < 4; ++r) {
        int row = m0 + wm * 64 + m * 16 + hi * 4 + r; // 0..8191
        int b = row >> 11, s = row & 2047;
        dst[(((size_t)b * H_ + h) * S_ + s) * HD_ + hd] = f2bf(acc[m][n][r] + bv);
      }
    }
}

// GEMM2: out = ctx @ W_proj + b ; fp32 out
__global__ __launch_bounds__(256, 2)
void k_gemm_proj(const unsigned short* __restrict__ A, const unsigned short* __restrict__ Bt,
                 const float* __restrict__ bias, float* __restrict__ C, int N) {
  __shared__ unsigned short sm[2 * 8192];
  const int m0 = blockIdx.y * 128, n0 = blockIdx.x * 128;
  f32x4 acc[4][4];
  gemm_core(A, Bt, 1024, m0, n0, sm, acc);
  const int t = threadIdx.x, w = t >> 6, l = t & 63;
  const int wm = w >> 1, wn = w & 1, lo = l & 15, hi = l >> 4;
#pragma unroll
  for (int m = 0; m < 4; ++m)
#pragma unroll
    for (int n = 0; n < 4; ++n) {
      int col = n0 + wn * 64 + n * 16 + lo;
      float bv = bias[col];
#pragma unroll
      for (int r = 0; r < 4; ++r) {
        int row = m0 + wm * 64 + m * 16 + hi * 4 + r;
        C[(size_t)row * N + col] = acc[m][n][r] + bv;
      }
    }
}

// ---------------------------------------------------------------- attention
// Block = (bh, 128 q rows); 4 waves, each owns 32 q rows (2 m-frags at
// q0+m*64+w*16). KV tiles of 64. Q frags in regs; K,V in padded LDS;
// P via per-wave LDS. Online softmax with wave-parallel shfl_xor row-reduce.
__global__ __launch_bounds__(256, 2)
void k_attn(const unsigned short* __restrict__ Qh, const unsigned short* __restrict__ Kh,
            const unsigned short* __restrict__ Vt, unsigned short* __restrict__ ctx) {
  __shared__ unsigned short Kl[64][72];
  __shared__ unsigned short Vl[64][72];
  __shared__ unsigned short Pl[4][32][72];
  const int bh = blockIdx.y;
  const int q0 = blockIdx.x * 128;
  const int t = threadIdx.x, w = t >> 6, l = t & 63, lo = l & 15, hi = l >> 4;
  const unsigned short* Qb = Qh + (size_t)bh * S_ * HD_;
  const unsigned short* Kb = Kh + (size_t)bh * S_ * HD_;
  const unsigned short* Vb = Vt + (size_t)bh * S_ * HD_;   // [HD][S]

  s16x8 qf[2][2];
  int qr[2];
#pragma unroll
  for (int m = 0; m < 2; ++m) {
    qr[m] = q0 + m * 64 + w * 16;
#pragma unroll
    for (int kk = 0; kk < 2; ++kk)
      qf[m][kk] = *(const s16x8*)(Qb + (size_t)(qr[m] + lo) * HD_ + kk * 32 + hi * 8);
  }

  f32x4 O[2][4];
#pragma unroll
  for (int m = 0; m < 2; ++m)
#pragma unroll
    for (int n = 0; n < 4; ++n) O[m][n] = (f32x4){0.f, 0.f, 0.f, 0.f};
  float mrun[2][4], lrun[2][4];
#pragma unroll
  for (int m = 0; m < 2; ++m)
#pragma unroll
    for (int r = 0; r < 4; ++r) { mrun[m][r] = -1e30f; lrun[m][r] = 0.f; }

  const int ntiles = (q0 >> 6) + 2;
  for (int kt = 0; kt < ntiles; ++kt) {
    const int kv0 = kt * 64;
    __syncthreads();                       // protect Kl/Vl from prior readers
#pragma unroll
    for (int j = 0; j < 2; ++j) {          // stage K tile + V tile (8KB each)
      int ci = t + j * 256;
      int r = ci >> 3, o = (ci & 7) * 8;
      *(u16x8*)&Kl[r][o] = *(const u16x8*)(Kb + (size_t)(kv0 + r) * HD_ + o);
      *(u16x8*)&Vl[r][o] = *(const u16x8*)(Vb + (size_t)r * S_ + kv0 + o);
    }
    __syncthreads();

    // S = Q K^T
    s16x8 kf[4][2];
#pragma unroll
    for (int n = 0; n < 4; ++n)
#pragma unroll
      for (int kk = 0; kk < 2; ++kk)
        kf[n][kk] = *(const s16x8*)&Kl[n * 16 + lo][kk * 32 + hi * 8];
    f32x4 s[2][4];
#pragma unroll
    for (int m = 0; m < 2; ++m)
#pragma unroll
      for (int n = 0; n < 4; ++n) s[m][n] = (f32x4){0.f, 0.f, 0.f, 0.f};
#pragma unroll
    for (int kk = 0; kk < 2; ++kk)
#pragma unroll
      for (int m = 0; m < 2; ++m)
#pragma unroll
        for (int n = 0; n < 4; ++n)
          s[m][n] = __builtin_amdgcn_mfma_f32_16x16x32_bf16(qf[m][kk], kf[n][kk], s[m][n], 0, 0, 0);

    // online softmax (per m-frag: 4 rows/lane, cols = kv0 + n*16 + lo)
#pragma unroll
    for (int m = 0; m < 2; ++m) {
      float p[4][4];
      float rmax[4] = {-1e30f, -1e30f, -1e30f, -1e30f};
#pragma unroll
      for (int n = 0; n < 4; ++n)
#pragma unroll
        for (int r = 0; r < 4; ++r) {
          float v = s[m][n][r] * 0.125f;               // 1/sqrt(64)
          int cg = kv0 + n * 16 + lo;
          int qg = qr[m] + hi * 4 + r;
          v = (cg <= qg) ? v : -1e30f;                 // causal mask
          p[n][r] = v;
          rmax[r] = fmaxf(rmax[r], v);
        }
#pragma unroll
      for (int r = 0; r < 4; ++r) {
        float v = rmax[r];
        v = fmaxf(v, __shfl_xor(v, 1));
        v = fmaxf(v, __shfl_xor(v, 2));
        v = fmaxf(v, __shfl_xor(v, 4));
        v = fmaxf(v, __shfl_xor(v, 8));
        rmax[r] = v;
      }
      float alpha[4];
#pragma unroll
      for (int r = 0; r < 4; ++r) {
        float mnew = fmaxf(mrun[m][r], rmax[r]);
        alpha[r] = __expf(mrun[m][r] - mnew);
        mrun[m][r] = mnew;
      }
      float rsum[4] = {0.f, 0.f, 0.f, 0.f};
#pragma unroll
      for (int n = 0; n < 4; ++n)
#pragma unroll
        for (int r = 0; r < 4; ++r) {
          float e = __expf(p[n][r] - mrun[m][r]);      // masked: exp(-1e30-m)=0
          p[n][r] = e;
          rsum[r] += e;
        }
#pragma unroll
      for (int r = 0; r < 4; ++r) {
        float v = rsum[r];
        v += __shfl_xor(v, 1);
        v += __shfl_xor(v, 2);
        v += __shfl_xor(v, 4);
        v += __shfl_xor(v, 8);
        lrun[m][r] = lrun[m][r] * alpha[r] + v;
      }
#pragma unroll
      for (int n = 0; n < 4; ++n)
#pragma unroll
        for (int r = 0; r < 4; ++r) O[m][n][r] *= alpha[r];
#pragma unroll
      for (int n = 0; n < 4; ++n)
#pragma unroll
        for (int r = 0; r < 4; ++r)
          Pl[w][m * 16 + hi * 4 + r][n * 16 + lo] = f2bf(p[n][r]);
    }

    // O += P V   (P: A-op from per-wave LDS; V: B-op from Vl[hd][kv])
#pragma unroll
    for (int kk = 0; kk < 2; ++kk) {
      s16x8 pa0 = *(const s16x8*)&Pl[w][lo][kk * 32 + hi * 8];
      s16x8 pa1 = *(const s16x8*)&Pl[w][16 + lo][kk * 32 + hi * 8];
#pragma unroll
      for (int n = 0; n < 4; ++n) {
        s16x8 vf = *(const s16x8*)&Vl[n * 16 + lo][kk * 32 + hi * 8];
        O[0][n] = __builtin_amdgcn_mfma_f32_16x16x32_bf16(pa0, vf, O[0][n], 0, 0, 0);
        O[1][n] = __builtin_amdgcn_mfma_f32_16x16x32_bf16(pa1, vf, O[1][n], 0, 0, 0);
      }
    }
  }

  // epilogue: ctx[B,S,H,HD] bf16
  const int b = bh >> 4, h = bh & 15;
#pragma unroll
  for (int m = 0; m < 2; ++m) {
    float inv[4];
#pragma unroll
    for (int r = 0; r < 4; ++r) inv[r] = 1.0f / lrun[m][r];
#pragma unroll
    for (int n = 0; n < 4; ++n)
#pragma unroll
      for (int r = 0; r < 4; ++r) {
        int qg = qr[m] + hi * 4 + r;
        int hd = n * 16 + lo;
        ctx[(((size_t)(b * S_ + qg)) * H_ + h) * HD_ + hd] = f2bf(O[m][n][r] * inv[r]);
      }
  }
}

// ---------------------------------------------------------------- launch
extern "C" void kernel_launch(void* const* d_in, const int* in_sizes, int n_in,
                              void* d_out, int out_size, void* d_ws, size_t ws_size,
                              hipStream_t stream) {
  const float* x      = (const float*)d_in[0];
  const float* W_attn = (const float*)d_in[1];
  const float* b_attn = (const float*)d_in[2];
  const float* W_proj = (const float*)d_in[3];
  const float* b_proj = (const float*)d_in[4];
  float* out = (float*)d_out;

  char* ws = (char*)d_ws;
  size_t off = 0;
  auto alloc = [&](size_t bytes) {
    char* p = ws + off;
    off += (bytes + 255) & ~(size_t)255;
    return p;
  };
  unsigned short* xb  = (unsigned short*)alloc((size_t)8192 * 1024 * 2);  // x bf16
  unsigned short* Wta = (unsigned short*)alloc((size_t)3072 * 1024 * 2);  // W_attn^T bf16
  unsigned short* Wtp = (unsigned short*)alloc((size_t)1024 * 1024 * 2);  // W_proj^T bf16
  unsigned short* Qh  = (unsigned short*)alloc((size_t)64 * 2048 * 64 * 2);
  unsigned short* Kh  = (unsigned short*)alloc((size_t)64 * 2048 * 64 * 2);
  unsigned short* Vh  = (unsigned short*)alloc((size_t)64 * 2048 * 64 * 2);
  unsigned short* Vt  = (unsigned short*)alloc((size_t)64 * 2048 * 64 * 2);
  unsigned short* ctx = (unsigned short*)alloc((size_t)8192 * 1024 * 2);

  k_cvt<<<dim3(2048), dim3(256), 0, stream>>>(x, xb, (8192 * 1024) / 4);
  k_tpose_cvt<<<dim3(48, 16), dim3(256), 0, stream>>>(W_attn, Wta, 1024, 3072);
  k_tpose_cvt<<<dim3(16, 16), dim3(256), 0, stream>>>(W_proj, Wtp, 1024, 1024);
  k_gemm_qkv<<<dim3(24, 64), dim3(256), 0, stream>>>(xb, Wta, b_attn, Qh, Kh, Vh);
  k_tpose_v<<<dim3(32, 64), dim3(256), 0, stream>>>(Vh, Vt);
  k_attn<<<dim3(16, 64), dim3(256), 0, stream>>>(Qh, Kh, Vt, ctx);
  k_gemm_proj<<<dim3(8, 64), dim3(256), 0, stream>>>(ctx, Wtp, b_proj, out, 1024);
}

// Round 3
// 195.836 us; speedup vs baseline: 1.7060x; 1.7060x over previous
//
#include <hip/hip_runtime.h>
#include <hip/hip_bf16.h>
#include <stdint.h>

// Problem constants: B=4, S=2048, D=1024, H=16, HD=64
#define B_  4
#define S_  2048
#define D_  1024
#define H_  16
#define HD_ 64

typedef __attribute__((ext_vector_type(8))) short          s16x8;   // MFMA A/B frag (8 bf16)
typedef __attribute__((ext_vector_type(4))) float          f32x4;   // MFMA C/D frag
typedef __attribute__((ext_vector_type(8))) unsigned short u16x8;   // 16B bf16 chunk

__device__ __forceinline__ unsigned short f2bf(float f) {
  union { float f; unsigned int u; } v; v.f = f;
  unsigned int u = v.u;
  u += 0x7fffu + ((u >> 16) & 1u);       // RNE
  return (unsigned short)(u >> 16);
}

// ---------------------------------------------------------------- converts
__global__ void k_cvt(const float* __restrict__ src, unsigned short* __restrict__ dst, int n4) {
  int i = blockIdx.x * blockDim.x + threadIdx.x;
  int stride = gridDim.x * blockDim.x;
  for (int j = i; j < n4; j += stride) {
    float4 v = reinterpret_cast<const float4*>(src)[j];
    ushort4 o;
    o.x = f2bf(v.x); o.y = f2bf(v.y); o.z = f2bf(v.z); o.w = f2bf(v.w);
    reinterpret_cast<ushort4*>(dst)[j] = o;
  }
}

// fp32 [R][C] -> bf16 [C][R]   (weights -> B^T layout for gemm-BT)
__global__ void k_tpose_cvt(const float* __restrict__ src, unsigned short* __restrict__ dst,
                            int R, int C) {
  __shared__ unsigned short tile[64][72];
  int c0 = blockIdx.x * 64, r0 = blockIdx.y * 64;
  int tx = threadIdx.x & 63, ty = threadIdx.x >> 6;
#pragma unroll
  for (int i = 0; i < 16; ++i) {
    int r = ty * 16 + i;
    tile[r][tx] = f2bf(src[(size_t)(r0 + r) * C + c0 + tx]);
  }
  __syncthreads();
#pragma unroll
  for (int i = 0; i < 16; ++i) {
    int c = ty * 16 + i;
    dst[(size_t)(c0 + c) * R + r0 + tx] = tile[tx][c];
  }
}

// bf16 V [BH][S][HD] -> Vt [BH][HD][S]
__global__ void k_tpose_v(const unsigned short* __restrict__ src, unsigned short* __restrict__ dst) {
  __shared__ unsigned short tile[64][72];
  int s0 = blockIdx.x * 64, bh = blockIdx.y;
  int tx = threadIdx.x & 63, ty = threadIdx.x >> 6;
  const unsigned short* sb = src + (size_t)bh * S_ * HD_;
  unsigned short*       db = dst + (size_t)bh * S_ * HD_;
#pragma unroll
  for (int i = 0; i < 16; ++i) {
    int r = ty * 16 + i;
    tile[r][tx] = sb[(size_t)(s0 + r) * HD_ + tx];
  }
  __syncthreads();
#pragma unroll
  for (int i = 0; i < 16; ++i) {
    int hd = ty * 16 + i;
    db[(size_t)hd * S_ + s0 + tx] = tile[tx][hd];
  }
}

// ---------------------------------------------------------------- GEMM core
__device__ __forceinline__ void gemm_core(const unsigned short* __restrict__ A,
                                          const unsigned short* __restrict__ Bt,
                                          int K, int m0, int n0,
                                          unsigned short* sm, f32x4 acc[4][4]) {
  const int t = threadIdx.x;
  const int w = t >> 6, l = t & 63;
  const int wm = w >> 1, wn = w & 1;
  const int lo = l & 15, hi = l >> 4;

  const int ci0 = t, ci1 = t + 256;
  const int r0c = ci0 >> 2, o0c = ci0 & 3;
  const int r1c = ci1 >> 2, o1c = ci1 & 3;
  const int swz0 = r0c * 32 + ((o0c ^ ((r0c >> 1) & 3)) << 3);
  const int swz1 = r1c * 32 + ((o1c ^ ((r1c >> 1) & 3)) << 3);
  const unsigned short* gA0 = A  + (size_t)(m0 + r0c) * K + o0c * 8;
  const unsigned short* gA1 = A  + (size_t)(m0 + r1c) * K + o1c * 8;
  const unsigned short* gB0 = Bt + (size_t)(n0 + r0c) * K + o0c * 8;
  const unsigned short* gB1 = Bt + (size_t)(n0 + r1c) * K + o1c * 8;

#pragma unroll
  for (int m = 0; m < 4; ++m)
#pragma unroll
    for (int n = 0; n < 4; ++n)
      acc[m][n] = (f32x4){0.f, 0.f, 0.f, 0.f};

  const int NT = K >> 5;  // BK = 32
  u16x8 ra0 = *(const u16x8*)gA0, ra1 = *(const u16x8*)gA1;
  u16x8 rb0 = *(const u16x8*)gB0, rb1 = *(const u16x8*)gB1;

  for (int kt = 0; kt < NT; ++kt) {
    unsigned short* buf = sm + (kt & 1) * 8192;
    if (kt) __syncthreads();
    *(u16x8*)(buf + swz0)        = ra0;
    *(u16x8*)(buf + swz1)        = ra1;
    *(u16x8*)(buf + 4096 + swz0) = rb0;
    *(u16x8*)(buf + 4096 + swz1) = rb1;
    if (kt + 1 < NT) {
      int k0 = (kt + 1) << 5;
      ra0 = *(const u16x8*)(gA0 + k0);
      ra1 = *(const u16x8*)(gA1 + k0);
      rb0 = *(const u16x8*)(gB0 + k0);
      rb1 = *(const u16x8*)(gB1 + k0);
    }
    __syncthreads();
    const unsigned short* Ab = buf;
    const unsigned short* Bb = buf + 4096;
    s16x8 af[4], bfr[4];
#pragma unroll
    for (int m = 0; m < 4; ++m) {
      int row = wm * 64 + m * 16 + lo;
      af[m] = *(const s16x8*)(Ab + row * 32 + ((hi ^ ((row >> 1) & 3)) << 3));
    }
#pragma unroll
    for (int n = 0; n < 4; ++n) {
      int row = wn * 64 + n * 16 + lo;
      bfr[n] = *(const s16x8*)(Bb + row * 32 + ((hi ^ ((row >> 1) & 3)) << 3));
    }
    __builtin_amdgcn_s_setprio(1);
#pragma unroll
    for (int m = 0; m < 4; ++m)
#pragma unroll
      for (int n = 0; n < 4; ++n)
        acc[m][n] = __builtin_amdgcn_mfma_f32_16x16x32_bf16(af[m], bfr[n], acc[m][n], 0, 0, 0);
    __builtin_amdgcn_s_setprio(0);
  }
}

// GEMM1: qkv = x @ W_attn + b ; scatter into Q/K/V [B,H,S,HD] bf16.
// Q is pre-scaled by 0.125*log2(e) so attention runs in exp2 domain.
__global__ __launch_bounds__(256, 2)
void k_gemm_qkv(const unsigned short* __restrict__ A, const unsigned short* __restrict__ Bt,
                const float* __restrict__ bias,
                unsigned short* __restrict__ Qh, unsigned short* __restrict__ Kh,
                unsigned short* __restrict__ Vh) {
  __shared__ unsigned short sm[2 * 8192];
  const int m0 = blockIdx.y * 128, n0 = blockIdx.x * 128;
  f32x4 acc[4][4];
  gemm_core(A, Bt, 1024, m0, n0, sm, acc);
  const int t = threadIdx.x, w = t >> 6, l = t & 63;
  const int wm = w >> 1, wn = w & 1, lo = l & 15, hi = l >> 4;
#pragma unroll
  for (int m = 0; m < 4; ++m)
#pragma unroll
    for (int n = 0; n < 4; ++n) {
      int col = n0 + wn * 64 + n * 16 + lo;           // 0..3071
      float bv = bias[col];
      int sel = col >> 10, cw = col & 1023, h = cw >> 6, hd = cw & 63;
      float scl = (sel == 0) ? 0.18033688011112042f : 1.0f;  // log2(e)/8
      unsigned short* dst = (sel == 0) ? Qh : ((sel == 1) ? Kh : Vh);
#pragma unroll
      for (int r = 0; r < 4; ++r) {
        int row = m0 + wm * 64 + m * 16 + hi * 4 + r;
        int b = row >> 11, s = row & 2047;
        dst[(((size_t)b * H_ + h) * S_ + s) * HD_ + hd] = f2bf((acc[m][n][r] + bv) * scl);
      }
    }
}

// GEMM2: out = ctx @ W_proj + b ; fp32 out
__global__ __launch_bounds__(256, 2)
void k_gemm_proj(const unsigned short* __restrict__ A, const unsigned short* __restrict__ Bt,
                 const float* __restrict__ bias, float* __restrict__ C, int N) {
  __shared__ unsigned short sm[2 * 8192];
  const int m0 = blockIdx.y * 128, n0 = blockIdx.x * 128;
  f32x4 acc[4][4];
  gemm_core(A, Bt, 1024, m0, n0, sm, acc);
  const int t = threadIdx.x, w = t >> 6, l = t & 63;
  const int wm = w >> 1, wn = w & 1, lo = l & 15, hi = l >> 4;
#pragma unroll
  for (int m = 0; m < 4; ++m)
#pragma unroll
    for (int n = 0; n < 4; ++n) {
      int col = n0 + wn * 64 + n * 16 + lo;
      float bv = bias[col];
#pragma unroll
      for (int r = 0; r < 4; ++r) {
        int row = m0 + wm * 64 + m * 16 + hi * 4 + r;
        C[(size_t)row * N + col] = acc[m][n][r] + bv;
      }
    }
}

// ---------------------------------------------------------------- attention
// Swapped QK^T (mfma(K,Q)): lane (lo,hi) holds S[kv][q=lo] for 16 kv values.
// K rows are stored PERMUTED in LDS (slot = (kv&32)|((kv&1)<<4)|((kv>>1)&15))
// so those 16 values are exactly kv = 32c + 8hi + 2r + (n&1): after cvt_pk
// pairs the PV A-fragment is already lane-resident (zero shuffles for P).
// K/V LDS tiles use the G4 XOR chunk swizzle. Blocks pair q-tiles (i,15-i):
// uniform 34 KV tiles per block.
// FIX vs round 2: stage BOTH halves of each 64-row tile (2 chunks/thread per
// matrix = 8KB each); round 2 staged only rows 0..31 -> garbage upper half.
__global__ __launch_bounds__(256, 2)
void k_attn(const unsigned short* __restrict__ Qh, const unsigned short* __restrict__ Kh,
            const unsigned short* __restrict__ Vt, unsigned short* __restrict__ ctx) {
  __shared__ unsigned short Kl[4096];   // [slot 64][hd 64], swizzled
  __shared__ unsigned short Vl[4096];   // [hd 64][kv 64],  swizzled
  const int bh = blockIdx.y;
  const int t = threadIdx.x, w = t >> 6, l = t & 63, lo = l & 15, hi = l >> 4;
  const unsigned short* Qb = Qh + (size_t)bh * S_ * HD_;
  const unsigned short* Kb = Kh + (size_t)bh * S_ * HD_;
  const unsigned short* Vb = Vt + (size_t)bh * S_ * HD_;   // [HD][S]
  const int bb = bh >> 4, h = bh & 15;

  // staging geometry: thread t handles rows r0 (=t>>3) and r1 (=r0+32),
  // 16B chunk schunk within each row; 256 thr x 2 chunks x 16B = 8KB/matrix
  const int r0s = t >> 3, schunk = t & 7;
  const int r1s = r0s + 32;
  const int ks0 = (r0s & 32) | ((r0s & 1) << 4) | ((r0s >> 1) & 15);
  const int ks1 = (r1s & 32) | ((r1s & 1) << 4) | ((r1s >> 1) & 15);
  unsigned short* kdst0 = &Kl[ks0 * 64 + 8 * (schunk ^ (ks0 & 7))];
  unsigned short* kdst1 = &Kl[ks1 * 64 + 8 * (schunk ^ (ks1 & 7))];
  unsigned short* vdst0 = &Vl[r0s * 64 + 8 * (schunk ^ (r0s & 7))];
  unsigned short* vdst1 = &Vl[r1s * 64 + 8 * (schunk ^ (r1s & 7))];
  const unsigned short* ksrc0 = Kb + r0s * HD_ + schunk * 8;          // + kv0*HD_
  const unsigned short* ksrc1 = Kb + r1s * HD_ + schunk * 8;
  const unsigned short* vsrc0 = Vb + (size_t)r0s * S_ + schunk * 8;   // + kv0
  const unsigned short* vsrc1 = Vb + (size_t)r1s * S_ + schunk * 8;

  for (int half = 0; half < 2; ++half) {
    const int iq = half ? (15 - (int)blockIdx.x) : (int)blockIdx.x;
    const int q0 = iq * 128;
    const int nt = (q0 >> 6) + 2;

    s16x8 qf[2][2];
    int qbase[2];
#pragma unroll
    for (int g = 0; g < 2; ++g) {
      qbase[g] = q0 + g * 64 + w * 16;
#pragma unroll
      for (int kk = 0; kk < 2; ++kk)
        qf[g][kk] = *(const s16x8*)(Qb + (size_t)(qbase[g] + lo) * HD_ + kk * 32 + hi * 8);
    }
    f32x4 O[2][4];
#pragma unroll
    for (int g = 0; g < 2; ++g)
#pragma unroll
      for (int nh = 0; nh < 4; ++nh) O[g][nh] = (f32x4){0.f, 0.f, 0.f, 0.f};
    float mrun[2] = {-1e30f, -1e30f}, lrun[2] = {0.f, 0.f};

    u16x8 rk0 = *(const u16x8*)ksrc0, rk1 = *(const u16x8*)ksrc1;   // tile 0
    u16x8 rv0 = *(const u16x8*)vsrc0, rv1 = *(const u16x8*)vsrc1;

    for (int kt = 0; kt < nt; ++kt) {
      const int kv0 = kt * 64;
      __syncthreads();                       // prior readers done
      *(u16x8*)kdst0 = rk0;
      *(u16x8*)kdst1 = rk1;
      *(u16x8*)vdst0 = rv0;
      *(u16x8*)vdst1 = rv1;
      if (kt + 1 < nt) {                     // prefetch next tile (hides HBM)
        rk0 = *(const u16x8*)(ksrc0 + (size_t)(kv0 + 64) * HD_);
        rk1 = *(const u16x8*)(ksrc1 + (size_t)(kv0 + 64) * HD_);
        rv0 = *(const u16x8*)(vsrc0 + kv0 + 64);
        rv1 = *(const u16x8*)(vsrc1 + kv0 + 64);
      }
      __syncthreads();

      // S^T = K Q^T : p[g][n][r] = S[kv0+32(n>>1)+8hi+2r+(n&1)][qbase[g]+lo]
      f32x4 p[2][4];
#pragma unroll
      for (int g = 0; g < 2; ++g)
#pragma unroll
        for (int n = 0; n < 4; ++n) p[g][n] = (f32x4){0.f, 0.f, 0.f, 0.f};
#pragma unroll
      for (int kk = 0; kk < 2; ++kk) {
        s16x8 kf[4];
#pragma unroll
        for (int n = 0; n < 4; ++n)
          kf[n] = *(const s16x8*)&Kl[(n * 16 + lo) * 64 + 8 * ((kk * 4 + hi) ^ (lo & 7))];
        __builtin_amdgcn_s_setprio(1);
#pragma unroll
        for (int g = 0; g < 2; ++g)
#pragma unroll
          for (int n = 0; n < 4; ++n)
            p[g][n] = __builtin_amdgcn_mfma_f32_16x16x32_bf16(kf[n], qf[g][kk], p[g][n], 0, 0, 0);
        __builtin_amdgcn_s_setprio(0);
      }

      union PU { unsigned int u[4]; s16x8 s; };
      PU pa[2][2];
#pragma unroll
      for (int g = 0; g < 2; ++g) {
        if (kv0 + 63 > qbase[g]) {           // wave-uniform: mask only diagonal tiles
          const int q = qbase[g] + lo;
#pragma unroll
          for (int n = 0; n < 4; ++n)
#pragma unroll
            for (int r = 0; r < 4; ++r) {
              int kv = kv0 + 32 * (n >> 1) + 8 * hi + 2 * r + (n & 1);
              p[g][n][r] = (kv <= q) ? p[g][n][r] : -1e30f;
            }
        }
        // row max: 15 in-lane + xor16/32 across the q-column lane group
        float mx = fmaxf(fmaxf(fmaxf(p[g][0][0], p[g][0][1]), fmaxf(p[g][0][2], p[g][0][3])),
                         fmaxf(fmaxf(p[g][1][0], p[g][1][1]), fmaxf(p[g][1][2], p[g][1][3])));
        mx = fmaxf(mx, fmaxf(fmaxf(fmaxf(p[g][2][0], p[g][2][1]), fmaxf(p[g][2][2], p[g][2][3])),
                             fmaxf(fmaxf(p[g][3][0], p[g][3][1]), fmaxf(p[g][3][2], p[g][3][3]))));
        mx = fmaxf(mx, __shfl_xor(mx, 16));
        mx = fmaxf(mx, __shfl_xor(mx, 32));
        float mnew = fmaxf(mrun[g], mx);
        float alpha = exp2f(mrun[g] - mnew);
        mrun[g] = mnew;
        float sum = 0.f;
#pragma unroll
        for (int n = 0; n < 4; ++n)
#pragma unroll
          for (int r = 0; r < 4; ++r) {
            float e = exp2f(p[g][n][r] - mnew);
            p[g][n][r] = e;
            sum += e;
          }
        sum += __shfl_xor(sum, 16);
        sum += __shfl_xor(sum, 32);
        lrun[g] = lrun[g] * alpha + sum;
        // O is in output layout (row q = 4hi+r): fetch alpha per output row
#pragma unroll
        for (int r = 0; r < 4; ++r) {
          float ar_ = __shfl(alpha, 4 * hi + r);
#pragma unroll
          for (int nh = 0; nh < 4; ++nh) O[g][nh][r] *= ar_;
        }
        // pack P -> PV A-fragment: already lane-resident, just cvt_pk pairs
#pragma unroll
        for (int c = 0; c < 2; ++c)
#pragma unroll
          for (int r = 0; r < 4; ++r) {
            unsigned int pk;
            asm("v_cvt_pk_bf16_f32 %0, %1, %2"
                : "=v"(pk) : "v"(p[g][2 * c][r]), "v"(p[g][2 * c + 1][r]));
            pa[g][c].u[r] = pk;
          }
      }

      // O += P V
#pragma unroll
      for (int c = 0; c < 2; ++c) {
        s16x8 vf[4];
#pragma unroll
        for (int nh = 0; nh < 4; ++nh)
          vf[nh] = *(const s16x8*)&Vl[(nh * 16 + lo) * 64 + 8 * ((4 * c + hi) ^ (lo & 7))];
        __builtin_amdgcn_s_setprio(1);
#pragma unroll
        for (int nh = 0; nh < 4; ++nh) {
          O[0][nh] = __builtin_amdgcn_mfma_f32_16x16x32_bf16(pa[0][c].s, vf[nh], O[0][nh], 0, 0, 0);
          O[1][nh] = __builtin_amdgcn_mfma_f32_16x16x32_bf16(pa[1][c].s, vf[nh], O[1][nh], 0, 0, 0);
        }
        __builtin_amdgcn_s_setprio(0);
      }
    }

    // epilogue: ctx[B,S,H,HD] bf16
#pragma unroll
    for (int g = 0; g < 2; ++g) {
#pragma unroll
      for (int r = 0; r < 4; ++r) {
        float li = 1.0f / __shfl(lrun[g], 4 * hi + r);
        int qg = qbase[g] + 4 * hi + r;
#pragma unroll
        for (int nh = 0; nh < 4; ++nh) {
          int hd = nh * 16 + lo;
          ctx[(((size_t)(bb * S_ + qg)) * H_ + h) * HD_ + hd] = f2bf(O[g][nh][r] * li);
        }
      }
    }
  }
}

// ---------------------------------------------------------------- launch
extern "C" void kernel_launch(void* const* d_in, const int* in_sizes, int n_in,
                              void* d_out, int out_size, void* d_ws, size_t ws_size,
                              hipStream_t stream) {
  const float* x      = (const float*)d_in[0];
  const float* W_attn = (const float*)d_in[1];
  const float* b_attn = (const float*)d_in[2];
  const float* W_proj = (const float*)d_in[3];
  const float* b_proj = (const float*)d_in[4];
  float* out = (float*)d_out;

  char* ws = (char*)d_ws;
  size_t off = 0;
  auto alloc = [&](size_t bytes) {
    char* p = ws + off;
    off += (bytes + 255) & ~(size_t)255;
    return p;
  };
  unsigned short* xb  = (unsigned short*)alloc((size_t)8192 * 1024 * 2);
  unsigned short* Wta = (unsigned short*)alloc((size_t)3072 * 1024 * 2);
  unsigned short* Wtp = (unsigned short*)alloc((size_t)1024 * 1024 * 2);
  unsigned short* Qh  = (unsigned short*)alloc((size_t)64 * 2048 * 64 * 2);
  unsigned short* Kh  = (unsigned short*)alloc((size_t)64 * 2048 * 64 * 2);
  unsigned short* Vh  = (unsigned short*)alloc((size_t)64 * 2048 * 64 * 2);
  unsigned short* Vt  = (unsigned short*)alloc((size_t)64 * 2048 * 64 * 2);
  unsigned short* ctx = (unsigned short*)alloc((size_t)8192 * 1024 * 2);

  k_cvt<<<dim3(2048), dim3(256), 0, stream>>>(x, xb, (8192 * 1024) / 4);
  k_tpose_cvt<<<dim3(48, 16), dim3(256), 0, stream>>>(W_attn, Wta, 1024, 3072);
  k_tpose_cvt<<<dim3(16, 16), dim3(256), 0, stream>>>(W_proj, Wtp, 1024, 1024);
  k_gemm_qkv<<<dim3(24, 64), dim3(256), 0, stream>>>(xb, Wta, b_attn, Qh, Kh, Vh);
  k_tpose_v<<<dim3(32, 64), dim3(256), 0, stream>>>(Vh, Vt);
  k_attn<<<dim3(8, 64), dim3(256), 0, stream>>>(Qh, Kh, Vt, ctx);
  k_gemm_proj<<<dim3(8, 64), dim3(256), 0, stream>>>(ctx, Wtp, b_proj, out, 1024);
}